// Round 22
// baseline (1412.919 us; speedup 1.0000x reference)
//
#include <hip/hip_runtime.h>
#include <hip/hip_bf16.h>
#include <stdint.h>

// ---------------------------------------------------------------------------
// MultiheadAttention (B=2,S=2048,E=2048,H=16,D=128), softcap=50, alpha=1
// Inputs FP32, output FP32, dict-order labels (proven r8-r21).
// Round 22: gemm8_qkv ring depth 4->2 (LDS 128->64KB) => 2 blocks/CU so all
// 384 blocks are co-resident (r21 diagnosis: 1-block/CU left a 128-block
// tail round = 25% idle chip; 808 TF ~= 75% of effective). vmcnt(12->4).
// Cross-block overlap (m97 mechanism) covers the shallower pipeline.
// attn (r18), gemm_out (m97+T1), cvt unchanged.
// ---------------------------------------------------------------------------

typedef __attribute__((ext_vector_type(8))) short s16x8;   // 8 bf16
typedef __attribute__((ext_vector_type(4))) float f32x4;

typedef const __attribute__((address_space(1))) char* gcptr;
typedef __attribute__((address_space(3))) char* lcptr;

#define MFMA_BF16(a, b, c) __builtin_amdgcn_mfma_f32_16x16x32_bf16((a), (b), (c), 0, 0, 0)

__device__ __forceinline__ short f2bf(float f) {          // fp32 -> bf16 RNE
  union { float f; unsigned u; } x; x.f = f;
  unsigned r = (x.u + 0x7fffu + ((x.u >> 16) & 1u)) >> 16;
  return (short)r;
}

__device__ __forceinline__ void gload16(const void* g, void* lds) {
  __builtin_amdgcn_global_load_lds((gcptr)g, (lcptr)lds, 16, 0, 0);
}

constexpr int GK = 2048;
constexpr int SL = 2048, EMB = 2048, HD = 128;

// ---------------------------------------------------------------------------
// Merged fp32 -> bf16 conversion (unchanged).
// ---------------------------------------------------------------------------
__global__ void cvt_all(const float* __restrict__ q, const float* __restrict__ k,
                        const float* __restrict__ v, const float* __restrict__ wq,
                        const float* __restrict__ wk, const float* __restrict__ wv,
                        const float* __restrict__ wo, short* __restrict__ dst) {
  const int N8A = 1 << 20, N8W = 1 << 19;
  const int total = 3 * N8A + 4 * N8W;
  int i = blockIdx.x * blockDim.x + threadIdx.x;
  int stride = gridDim.x * blockDim.x;
  for (; i < total; i += stride) {
    const float* src;
    size_t loc;
    if (i < 3 * N8A) {
      int sel = i >> 20;
      loc = (size_t)(i & (N8A - 1));
      src = sel == 0 ? q : (sel == 1 ? k : v);
    } else {
      int w = i - 3 * N8A;
      int sel = w >> 19;
      loc = (size_t)(w & (N8W - 1));
      src = sel == 0 ? wq : (sel == 1 ? wk : (sel == 2 ? wv : wo));
    }
    f32x4 a = *reinterpret_cast<const f32x4*>(src + loc * 8);
    f32x4 b = *reinterpret_cast<const f32x4*>(src + loc * 8 + 4);
    s16x8 w8;
#pragma unroll
    for (int j = 0; j < 4; ++j) { w8[j] = f2bf(a[j]); w8[4 + j] = f2bf(b[j]); }
    *reinterpret_cast<s16x8*>(dst + (size_t)i * 8) = w8;
  }
}

// ---------------------------------------------------------------------------
// 256^2 pipelined QKV GEMM — 2-region ring (64KB LDS, 2 blocks/CU).
// 512 thr / 8 waves (2x4); per-wave C = 128x64 (acc[8][4]); 64 K-halves.
// Phase: {issue H(n+1); vmcnt(4); bar; 12x ds_read; 32 MFMA @prio1; lgkm0;
// bar}. Granule swizzle: write lg=(c&3)^((c>>3)&3); read pg=g^((r>>1)&3).
// ---------------------------------------------------------------------------
__global__ __launch_bounds__(512, 4)
void gemm8_qkv(const short* __restrict__ a0, const short* __restrict__ a1,
               const short* __restrict__ w0, const short* __restrict__ w1,
               const short* __restrict__ w2, const short* __restrict__ a2,
               short* __restrict__ o0, short* __restrict__ o1,
               short* __restrict__ o2) {
  __shared__ __align__(16) short Lds[2 * 16384];   // 64 KiB

  const int z = blockIdx.z;
  const short* A = z == 0 ? a0 : (z == 1 ? a1 : w2);
  const short* B = z == 0 ? w0 : (z == 1 ? w1 : a2);
  short* C = z == 0 ? o0 : (z == 1 ? o1 : o2);
  const int gn = z == 2 ? 4096 : 2048;

  const int j = blockIdx.x + (blockIdx.y << 3);
  int bm, bn;
  if (z == 2) { bm = j & 7; bn = j >> 3; }
  else        { bm = ((j & 7) << 1) + ((j >> 3) & 1); bn = j >> 4; }

  const int tid = threadIdx.x;
  const int lane = tid & 63;
  const int wid = tid >> 6;
  const int wm = wid >> 2, wn = wid & 3;
  const int g = lane >> 4, r = lane & 15;
  const int pg = g ^ ((r >> 1) & 3);

  const size_t Abase = (size_t)bm * 256 * GK;
  const size_t Bbase = (size_t)bn * 256 * GK;

  const f32x4 fz = {0.f, 0.f, 0.f, 0.f};
  f32x4 acc[8][4];
#pragma unroll
  for (int m = 0; m < 8; ++m)
#pragma unroll
    for (int n = 0; n < 4; ++n) acc[m][n] = fz;

  auto issueHalf = [&](int n) {
    const int reg = (n & 1) * 16384;
    const int k0 = (n << 5) & (GK - 1);      // tail junk-issue is harmless
#pragma unroll
    for (int i = 0; i < 2; ++i) {
      int c = tid + i * 512;
      int row = c >> 2;
      int lg = (c & 3) ^ ((c >> 3) & 3);
      gload16(A + Abase + (size_t)row * GK + k0 + lg * 8, Lds + reg + c * 8);
    }
#pragma unroll
    for (int i = 0; i < 2; ++i) {
      int c = tid + i * 512;
      int row = c >> 2;
      int lg = (c & 3) ^ ((c >> 3) & 3);
      gload16(B + Bbase + (size_t)row * GK + k0 + lg * 8, Lds + reg + 8192 + c * 8);
    }
  };

  issueHalf(0);

  for (int t2 = 0; t2 < 32; ++t2) {
#pragma unroll
    for (int p = 0; p < 2; ++p) {
      const int n = t2 * 2 + p;
      // issue H(n+1) into region (n+1)&1 — its last reader was phase n-1,
      // whose trailing barrier every wave has already crossed.
      issueHalf(n + 1);
      // own H(n) landed (4 newest = H(n+1) allowed outstanding)...
      asm volatile("s_waitcnt vmcnt(4)" ::: "memory");
      // ...and everyone else's too:
      asm volatile("s_barrier" ::: "memory");

      const int areg = p * 16384;
      const short* Abuf = Lds + areg;
      const short* Bbuf = Lds + areg + 8192;

      s16x8 af[8], bf[4];
#pragma unroll
      for (int m = 0; m < 8; ++m)
        af[m] = *reinterpret_cast<const s16x8*>(
            Abuf + ((wm * 128 + m * 16 + r) << 5) + pg * 8);
#pragma unroll
      for (int nf = 0; nf < 4; ++nf)
        bf[nf] = *reinterpret_cast<const s16x8*>(
            Bbuf + ((wn * 64 + nf * 16 + r) << 5) + pg * 8);

      __builtin_amdgcn_s_setprio(1);
#pragma unroll
      for (int m = 0; m < 8; ++m)
#pragma unroll
        for (int nf = 0; nf < 4; ++nf)
          acc[m][nf] = MFMA_BF16(af[m], bf[nf], acc[m][nf]);
      __builtin_amdgcn_s_setprio(0);

      asm volatile("s_waitcnt lgkmcnt(0)" ::: "memory");
      asm volatile("s_barrier" ::: "memory"); // readers of H(n) done
    }
  }
  asm volatile("s_waitcnt vmcnt(0)" ::: "memory"); // quiesce tail junk loads

  // ---- epilogue: C write (bf16) ----
#pragma unroll
  for (int m = 0; m < 8; ++m)
#pragma unroll
    for (int jj = 0; jj < 4; ++jj) {
      int crow = bm * 256 + wm * 128 + m * 16 + g * 4 + jj;
      size_t off = (size_t)crow * gn + bn * 256 + wn * 64 + r;
#pragma unroll
      for (int nf = 0; nf < 4; ++nf) C[off + nf * 16] = f2bf(acc[m][nf][jj]);
    }
}

// ---------------------------------------------------------------------------
// Final GEMM (ctx @ Wo^T), m97 structure, fp32 out, T1 swizzle (unchanged).
// ---------------------------------------------------------------------------
__global__ __launch_bounds__(256, 2)
void gemm_out(const short* __restrict__ A, const short* __restrict__ B,
              float* __restrict__ C) {
  __shared__ __align__(16) short As[128 * 64];
  __shared__ __align__(16) short Bs[128 * 64];
  const int d = blockIdx.x + (blockIdx.y << 4);
  const int tile = ((d & 7) << 6) | (d >> 3);
  const int bm = tile >> 4, bn = tile & 15;

  const int tid = threadIdx.x;
  const int lane = tid & 63;
  const int wid = tid >> 6;
  const int wr = wid >> 1, wc = wid & 1;
  const int g = lane >> 4, r = lane & 15;

  const f32x4 fz = {0.f, 0.f, 0.f, 0.f};
  f32x4 acc[4][4];
#pragma unroll
  for (int m = 0; m < 4; ++m)
#pragma unroll
    for (int n = 0; n < 4; ++n) acc[m][n] = fz;

  const short* Ab = A + (size_t)bm * 128 * GK;
  const short* Bb = B + (size_t)bn * 128 * GK;

  for (int kt = 0; kt < GK; kt += 64) {
#pragma unroll
    for (int i = 0; i < 4; ++i) {
      int c = i * 256 + tid;
      int row = c >> 3, c8 = c & 7;
      gload16(Ab + (size_t)row * GK + kt + c8 * 8, As + c * 8);
      gload16(Bb + (size_t)row * GK + kt + c8 * 8, Bs + c * 8);
    }
    __syncthreads();
#pragma unroll
    for (int kk = 0; kk < 2; ++kk) {
      s16x8 af[4], bf[4];
#pragma unroll
      for (int m = 0; m < 4; ++m)
        af[m] = *reinterpret_cast<const s16x8*>(As + (wr * 64 + m * 16 + r) * 64 + kk * 32 + g * 8);
#pragma unroll
      for (int n = 0; n < 4; ++n)
        bf[n] = *reinterpret_cast<const s16x8*>(Bs + (wc * 64 + n * 16 + r) * 64 + kk * 32 + g * 8);
#pragma unroll
      for (int m = 0; m < 4; ++m)
#pragma unroll
        for (int n = 0; n < 4; ++n) acc[m][n] = MFMA_BF16(af[m], bf[n], acc[m][n]);
    }
    __syncthreads();
  }

#pragma unroll
  for (int m = 0; m < 4; ++m)
#pragma unroll
    for (int jj = 0; jj < 4; ++jj) {
      int crow = bm * 128 + wr * 64 + m * 16 + g * 4 + jj;
      size_t off = (size_t)crow * 2048 + bn * 128 + wc * 64 + r;
#pragma unroll
      for (int n = 0; n < 4; ++n) C[off + n * 16] = acc[m][n][jj];
    }
}

// ---------------------------------------------------------------------------
// MFMA flash attention (r18, unchanged).
// ---------------------------------------------------------------------------
__global__ __launch_bounds__(256, 2)
void attn(const short* __restrict__ Q, const short* __restrict__ K,
          const short* __restrict__ VT, short* __restrict__ O) {
  __shared__ __align__(16) short Ks[64 * 136];
  __shared__ __align__(16) short Vt[128 * 72];
  __shared__ __align__(16) short Ps[4][2][16 * 72];

  const int tid = threadIdx.x;
  const int lane = tid & 63;
  const int wid = tid >> 6;
  const int g = lane >> 4, r = lane & 15;

  const int dflat = blockIdx.x + (blockIdx.y << 4);
  const int cflat = ((dflat & 7) << 6) + (dflat >> 3);
  const int qb = cflat & 15;
  const int bh = cflat >> 4;
  const int b = bh >> 4, h = bh & 15;
  const size_t base = (size_t)b * SL * EMB + (size_t)h * HD;
  const size_t vbase = (size_t)h * HD * 4096 + (size_t)b * SL;

  const int q0 = qb * 128 + wid * 32;
  s16x8 qf[2][4];
#pragma unroll
  for (int s = 0; s < 2; ++s)
#pragma unroll
    for (int kk = 0; kk < 4; ++kk)
      qf[s][kk] = *reinterpret_cast<const s16x8*>(
          Q + base + (size_t)(q0 + s * 16 + r) * EMB + kk * 32 + g * 8);

  const f32x4 fz = {0.f, 0.f, 0.f, 0.f};
  float l_run[2][4];
  f32x4 acc_o[2][8];
#pragma unroll
  for (int s = 0; s < 2; ++s) {
#pragma unroll
    for (int i = 0; i < 4; ++i) l_run[s][i] = 0.f;
#pragma unroll
    for (int i = 0; i < 8; ++i) acc_o[s][i] = fz;
  }

  const float SCALE = 0.08838834764831845f;
  const float C50I = 0.02f;
  const float CA = -1.f / 3.f, CB = 2.f / 15.f;

  const int rk = tid >> 4, ck = tid & 15;
  const int rv = tid >> 3, cv = tid & 7;
  const int cvx = cv ^ (rv & 7);
  s16x8 kreg[4], vreg[4];
#pragma unroll
  for (int i = 0; i < 4; ++i) {
    kreg[i] = *reinterpret_cast<const s16x8*>(K + base + (size_t)(rk + i * 16) * EMB + ck * 8);
    vreg[i] = *reinterpret_cast<const s16x8*>(VT + vbase + (size_t)(rv + i * 32) * 4096 + cv * 8);
  }

  for (int t = 0; t < SL / 64; ++t) {
    __syncthreads();
#pragma unroll
    for (int i = 0; i < 4; ++i) {
      *reinterpret_cast<s16x8*>(&Ks[(rk + i * 16) * 136 + ck * 8]) = kreg[i];
      *reinterpret_cast<s16x8*>(&Vt[(rv + i * 32) * 72 + (cvx << 3)]) = vreg[i];
    }
    __syncthreads();

    if (t + 1 < SL / 64) {
      const int kv1 = (t + 1) * 64;
#pragma unroll
      for (int i = 0; i < 4; ++i) {
        kreg[i] = *reinterpret_cast<const s16x8*>(K + base + (size_t)(kv1 + rk + i * 16) * EMB + ck * 8);
        vreg[i] = *reinterpret_cast<const s16x8*>(VT + vbase + (size_t)(rv + i * 32) * 4096 + kv1 + cv * 8);
      }
    }

    f32x4 sv[2][4];
    __builtin_amdgcn_s_setprio(1);
#pragma unroll
    for (int kn = 0; kn < 4; ++kn) {
      sv[0][kn] = fz; sv[1][kn] = fz;
#pragma unroll
      for (int kk = 0; kk < 4; ++kk) {
        s16x8 kf = *reinterpret_cast<const s16x8*>(&Ks[(kn * 16 + r) * 136 + kk * 32 + g * 8]);
        sv[0][kn] = MFMA_BF16(qf[0][kk], kf, sv[0][kn]);
        sv[1][kn] = MFMA_BF16(qf[1][kk], kf, sv[1][kn]);
      }
    }
    __builtin_amdgcn_s_setprio(0);

#pragma unroll
    for (int s = 0; s < 2; ++s)
#pragma unroll
      for (int kn = 0; kn < 4; ++kn)
#pragma unroll
        for (int reg = 0; reg < 4; ++reg) {
          float z = sv[s][kn][reg] * SCALE;
          float x = z * C50I;
          float x2 = x * x;
          float poly = __builtin_fmaf(x2, __builtin_fmaf(x2, CB, CA), 1.f);
          float cap = fminf(z * poly, 50.f);
          float pe = __expf(cap - 50.f);
          l_run[s][reg] += pe;
          sv[s][kn][reg] = pe;
        }

#pragma unroll
    for (int s = 0; s < 2; ++s)
#pragma unroll
      for (int kn = 0; kn < 4; ++kn)
#pragma unroll
        for (int reg = 0; reg < 4; ++reg)
          Ps[wid][s][(g * 4 + reg) * 72 + kn * 16 + r] = f2bf(sv[s][kn][reg]);

    __builtin_amdgcn_s_setprio(1);
#pragma unroll
    for (int c = 0; c < 2; ++c) {
      s16x8 pa0 = *reinterpret_cast<const s16x8*>(&Ps[wid][0][r * 72 + c * 32 + g * 8]);
      s16x8 pa1 = *reinterpret_cast<const s16x8*>(&Ps[wid][1][r * 72 + c * 32 + g * 8]);
#pragma unroll
      for (int dn = 0; dn < 8; ++dn) {
        int d = dn * 16 + r;
        int pc = ((c * 4 + g) ^ (r & 7));
        s16x8 vf = *reinterpret_cast<const s16x8*>(&Vt[d * 72 + (pc << 3)]);
        acc_o[0][dn] = MFMA_BF16(pa0, vf, acc_o[0][dn]);
        acc_o[1][dn] = MFMA_BF16(pa1, vf, acc_o[1][dn]);
      }
    }
    __builtin_amdgcn_s_setprio(0);
  }

#pragma unroll
  for (int s = 0; s < 2; ++s) {
#pragma unroll
    for (int reg = 0; reg < 4; ++reg) {
#pragma unroll
      for (int off = 1; off < 16; off <<= 1)
        l_run[s][reg] += __shfl_xor(l_run[s][reg], off);
      l_run[s][reg] = 1.f / l_run[s][reg];
    }
#pragma unroll
    for (int dn = 0; dn < 8; ++dn)
#pragma unroll
      for (int reg = 0; reg < 4; ++reg) {
        int row = q0 + s * 16 + g * 4 + reg;
        O[base + (size_t)row * EMB + dn * 16 + r] = f2bf(acc_o[s][dn][reg] * l_run[s][reg]);
      }
  }
}

__global__ void fill_f32(float* p, int n, float val) {
  int i = blockIdx.x * blockDim.x + threadIdx.x;
  if (i < n) p[i] = val;
}

// ---------------------------------------------------------------------------
extern "C" void kernel_launch(void* const* d_in, const int* in_sizes, int n_in,
                              void* d_out, int out_size, void* d_ws, size_t ws_size,
                              hipStream_t stream) {
  const float* q  = (const float*)d_in[0];
  const float* k  = (const float*)d_in[1];
  const float* v  = (const float*)d_in[2];
  const float* wq = (const float*)d_in[3];
  const float* wk = (const float*)d_in[4];
  const float* wv = (const float*)d_in[5];
  const float* wo = (const float*)d_in[6];
  float* out = (float*)d_out;

  bool ok = (n_in == 7) && out_size == 8388608;
  for (int i = 0; i < 3 && ok; ++i) ok = (in_sizes[i] == 8388608);
  for (int i = 3; i < 7 && ok; ++i) ok = (in_sizes[i] == 4194304);
  if (!ok) {
    fill_f32<<<(out_size + 255) / 256, 256, 0, stream>>>(out, out_size, 150.f);
    return;
  }

  const size_t NA = 8388608;
  const size_t NW = 4194304;
  const size_t need = (3 * NA + 4 * NW + 4 * NA) * sizeof(short); // 144 MiB
  if (ws_size < need) {
    fill_f32<<<(out_size + 255) / 256, 256, 0, stream>>>(out, out_size, 128.f);
    return;
  }

  short* bq  = (short*)d_ws;                 // cvt dst, contiguous
  short* bk  = bq + NA;
  short* bv  = bk + NA;
  short* bwq = bv + NA;
  short* bwk = bwq + NW;
  short* bwv = bwk + NW;
  short* bwo = bwv + NW;
  short* Qp  = bwo + NW;
  short* Kp  = Qp + NA;
  short* VpT = Kp + NA;                      // [2048 features][4096 tokens]
  short* Cx  = VpT + NA;

  dim3 g8(8, 16, 3);                         // 384 blocks x 512 threads
  dim3 gg(16, 32);                           // out GEMM (m97)
  dim3 ga(16, 32);                           // attn: 512 blocks

  cvt_all<<<2048, 256, 0, stream>>>(q, k, v, wq, wk, wv, wo, bq);
  gemm8_qkv<<<g8, dim3(512), 0, stream>>>(bq, bk, bwq, bwk, bwv, bv, Qp, Kp, VpT);
  attn<<<ga, dim3(256), 0, stream>>>(Qp, Kp, VpT, Cx);
  gemm_out<<<gg, dim3(256), 0, stream>>>(Cx, bwo, out);
}

// Round 23
// 323.347 us; speedup vs baseline: 4.3697x; 4.3697x over previous
//
#include <hip/hip_runtime.h>
#include <hip/hip_bf16.h>
#include <stdint.h>

// ---------------------------------------------------------------------------
// MultiheadAttention (B=2,S=2048,E=2048,H=16,D=128), softcap=50, alpha=1
// Inputs FP32, output FP32, dict-order labels (proven r8-r22).
// Round 23: REVERT to r20 (best measured 328.8us). r22's launch_bounds(512,4)
// capped VGPR at 128 -> acc[8][4] spilled to scratch (VGPR 64, 5.5GB
// scratch traffic, 1413us). The 256^2/8-wave structure is 1-block/CU by
// register budget; its 384-block tail (75% util) is structural.
// Pipeline: cvt_all -> gemm8_qkv (256^2 counted-vmcnt ring, 128KB LDS) ->
// attn (KVBLK=64, T14, XCD swizzle) -> gemm_out (m97+T1).
// ---------------------------------------------------------------------------

typedef __attribute__((ext_vector_type(8))) short s16x8;   // 8 bf16
typedef __attribute__((ext_vector_type(4))) float f32x4;

typedef const __attribute__((address_space(1))) char* gcptr;
typedef __attribute__((address_space(3))) char* lcptr;

#define MFMA_BF16(a, b, c) __builtin_amdgcn_mfma_f32_16x16x32_bf16((a), (b), (c), 0, 0, 0)

__device__ __forceinline__ short f2bf(float f) {          // fp32 -> bf16 RNE
  union { float f; unsigned u; } x; x.f = f;
  unsigned r = (x.u + 0x7fffu + ((x.u >> 16) & 1u)) >> 16;
  return (short)r;
}

__device__ __forceinline__ void gload16(const void* g, void* lds) {
  __builtin_amdgcn_global_load_lds((gcptr)g, (lcptr)lds, 16, 0, 0);
}

constexpr int GK = 2048;
constexpr int SL = 2048, EMB = 2048, HD = 128;

// ---------------------------------------------------------------------------
// Merged fp32 -> bf16 conversion (dst contiguous in ws).
// ---------------------------------------------------------------------------
__global__ void cvt_all(const float* __restrict__ q, const float* __restrict__ k,
                        const float* __restrict__ v, const float* __restrict__ wq,
                        const float* __restrict__ wk, const float* __restrict__ wv,
                        const float* __restrict__ wo, short* __restrict__ dst) {
  const int N8A = 1 << 20, N8W = 1 << 19;
  const int total = 3 * N8A + 4 * N8W;
  int i = blockIdx.x * blockDim.x + threadIdx.x;
  int stride = gridDim.x * blockDim.x;
  for (; i < total; i += stride) {
    const float* src;
    size_t loc;
    if (i < 3 * N8A) {
      int sel = i >> 20;
      loc = (size_t)(i & (N8A - 1));
      src = sel == 0 ? q : (sel == 1 ? k : v);
    } else {
      int w = i - 3 * N8A;
      int sel = w >> 19;
      loc = (size_t)(w & (N8W - 1));
      src = sel == 0 ? wq : (sel == 1 ? wk : (sel == 2 ? wv : wo));
    }
    f32x4 a = *reinterpret_cast<const f32x4*>(src + loc * 8);
    f32x4 b = *reinterpret_cast<const f32x4*>(src + loc * 8 + 4);
    s16x8 w8;
#pragma unroll
    for (int j = 0; j < 4; ++j) { w8[j] = f2bf(a[j]); w8[4 + j] = f2bf(b[j]); }
    *reinterpret_cast<s16x8*>(dst + (size_t)i * 8) = w8;
  }
}

// ---------------------------------------------------------------------------
// 256^2 pipelined QKV GEMM (r20). 512 thr / 8 waves (2x4); per-wave C =
// 128x64 (acc[8][4]); K-halves of 32 -> 64 phases; LDS ring of 4 regions x
// (A 256x32 + B 256x32) bf16 = 128KB. Granule swizzle: write content at
// phys granule (c&3) is logical (c&3)^((c>>3)&3); read phys g^((r>>1)&3).
// ---------------------------------------------------------------------------
__global__ __launch_bounds__(512, 1)
void gemm8_qkv(const short* __restrict__ a0, const short* __restrict__ a1,
               const short* __restrict__ w0, const short* __restrict__ w1,
               const short* __restrict__ w2, const short* __restrict__ a2,
               short* __restrict__ o0, short* __restrict__ o1,
               short* __restrict__ o2) {
  __shared__ __align__(16) short Lds[4 * 16384];   // 128 KiB

  const int z = blockIdx.z;
  const short* A = z == 0 ? a0 : (z == 1 ? a1 : w2);   // z=2: A=Wv (2048 rows)
  const short* B = z == 0 ? w0 : (z == 1 ? w1 : a2);   // z=2: B=v  (4096 rows)
  short* C = z == 0 ? o0 : (z == 1 ? o1 : o2);
  const int gn = z == 2 ? 4096 : 2048;

  // XCD-chunked bijective tile map (j = 0..127 per z).
  const int j = blockIdx.x + (blockIdx.y << 3);
  int bm, bn;
  if (z == 2) { bm = j & 7; bn = j >> 3; }             // 8 x 16
  else        { bm = ((j & 7) << 1) + ((j >> 3) & 1); bn = j >> 4; }  // 16 x 8

  const int tid = threadIdx.x;
  const int lane = tid & 63;
  const int wid = tid >> 6;                  // 0..7
  const int wm = wid >> 2, wn = wid & 3;     // 2 x 4 waves
  const int g = lane >> 4, r = lane & 15;
  const int pg = g ^ ((r >> 1) & 3);         // swizzled granule (lane-const)

  const size_t Abase = (size_t)bm * 256 * GK;
  const size_t Bbase = (size_t)bn * 256 * GK;

  const f32x4 fz = {0.f, 0.f, 0.f, 0.f};
  f32x4 acc[8][4];
#pragma unroll
  for (int m = 0; m < 8; ++m)
#pragma unroll
    for (int n = 0; n < 4; ++n) acc[m][n] = fz;

  // stage K-half n (32 K-cols) into region n&3: A (2 issues) + B (2).
  // chunk c = tid + i*512: row = c>>2, phys granule = c&3, LDS short-offset
  // = row*32 + (c&3)*8 = c*8.
  auto issueHalf = [&](int n) {
    const int reg = (n & 3) * 16384;
    const int k0 = (n << 5) & (GK - 1);      // modular tail-junk is harmless
#pragma unroll
    for (int i = 0; i < 2; ++i) {
      int c = tid + i * 512;
      int row = c >> 2;
      int lg = (c & 3) ^ ((c >> 3) & 3);
      gload16(A + Abase + (size_t)row * GK + k0 + lg * 8, Lds + reg + c * 8);
    }
#pragma unroll
    for (int i = 0; i < 2; ++i) {
      int c = tid + i * 512;
      int row = c >> 2;
      int lg = (c & 3) ^ ((c >> 3) & 3);
      gload16(B + Bbase + (size_t)row * GK + k0 + lg * 8, Lds + reg + 8192 + c * 8);
    }
  };

  issueHalf(0);
  issueHalf(1);
  issueHalf(2);

  for (int t2 = 0; t2 < 16; ++t2) {
#pragma unroll
    for (int p = 0; p < 4; ++p) {
      const int n = t2 * 4 + p;              // this phase's K-half
      // issue H(n+3) into region (n+3)&3 — its last reader was phase n-1,
      // whose trailing barrier every wave has already crossed.
      issueHalf(n + 3);
      // own H(n) loads landed (12 = 3 newer halves outstanding)...
      asm volatile("s_waitcnt vmcnt(12)" ::: "memory");
      // ...and everyone else's too:
      asm volatile("s_barrier" ::: "memory");

      const int areg = p * 16384;
      s16x8 af[8], bf[4];
#pragma unroll
      for (int m = 0; m < 8; ++m)
        af[m] = *reinterpret_cast<const s16x8*>(
            Lds + areg + ((wm * 128 + m * 16 + r) << 5) + pg * 8);
#pragma unroll
      for (int nf = 0; nf < 4; ++nf)
        bf[nf] = *reinterpret_cast<const s16x8*>(
            Lds + areg + 8192 + ((wn * 64 + nf * 16 + r) << 5) + pg * 8);

      __builtin_amdgcn_s_setprio(1);
#pragma unroll
      for (int m = 0; m < 8; ++m)
#pragma unroll
        for (int nf = 0; nf < 4; ++nf)
          acc[m][nf] = MFMA_BF16(af[m], bf[nf], acc[m][nf]);
      __builtin_amdgcn_s_setprio(0);

      asm volatile("s_waitcnt lgkmcnt(0)" ::: "memory");
      asm volatile("s_barrier" ::: "memory"); // readers of H(n) done
    }
  }
  asm volatile("s_waitcnt vmcnt(0)" ::: "memory"); // quiesce tail junk loads

  // ---- epilogue: C write (bf16) ----
#pragma unroll
  for (int m = 0; m < 8; ++m)
#pragma unroll
    for (int jj = 0; jj < 4; ++jj) {
      int crow = bm * 256 + wm * 128 + m * 16 + g * 4 + jj;
      size_t off = (size_t)crow * gn + bn * 256 + wn * 64 + r;
#pragma unroll
      for (int nf = 0; nf < 4; ++nf) C[off + nf * 16] = f2bf(acc[m][nf][jj]);
    }
}

// ---------------------------------------------------------------------------
// Final GEMM (ctx @ Wo^T), m97 structure, fp32 out, T1 swizzle.
// ---------------------------------------------------------------------------
__global__ __launch_bounds__(256, 2)
void gemm_out(const short* __restrict__ A, const short* __restrict__ B,
              float* __restrict__ C) {
  __shared__ __align__(16) short As[128 * 64];
  __shared__ __align__(16) short Bs[128 * 64];
  const int d = blockIdx.x + (blockIdx.y << 4);
  const int tile = ((d & 7) << 6) | (d >> 3);
  const int bm = tile >> 4, bn = tile & 15;

  const int tid = threadIdx.x;
  const int lane = tid & 63;
  const int wid = tid >> 6;
  const int wr = wid >> 1, wc = wid & 1;
  const int g = lane >> 4, r = lane & 15;

  const f32x4 fz = {0.f, 0.f, 0.f, 0.f};
  f32x4 acc[4][4];
#pragma unroll
  for (int m = 0; m < 4; ++m)
#pragma unroll
    for (int n = 0; n < 4; ++n) acc[m][n] = fz;

  const short* Ab = A + (size_t)bm * 128 * GK;
  const short* Bb = B + (size_t)bn * 128 * GK;

  for (int kt = 0; kt < GK; kt += 64) {
#pragma unroll
    for (int i = 0; i < 4; ++i) {
      int c = i * 256 + tid;
      int row = c >> 3, c8 = c & 7;
      gload16(Ab + (size_t)row * GK + kt + c8 * 8, As + c * 8);
      gload16(Bb + (size_t)row * GK + kt + c8 * 8, Bs + c * 8);
    }
    __syncthreads();
#pragma unroll
    for (int kk = 0; kk < 2; ++kk) {
      s16x8 af[4], bf[4];
#pragma unroll
      for (int m = 0; m < 4; ++m)
        af[m] = *reinterpret_cast<const s16x8*>(As + (wr * 64 + m * 16 + r) * 64 + kk * 32 + g * 8);
#pragma unroll
      for (int n = 0; n < 4; ++n)
        bf[n] = *reinterpret_cast<const s16x8*>(Bs + (wc * 64 + n * 16 + r) * 64 + kk * 32 + g * 8);
#pragma unroll
      for (int m = 0; m < 4; ++m)
#pragma unroll
        for (int n = 0; n < 4; ++n) acc[m][n] = MFMA_BF16(af[m], bf[n], acc[m][n]);
    }
    __syncthreads();
  }

#pragma unroll
  for (int m = 0; m < 4; ++m)
#pragma unroll
    for (int jj = 0; jj < 4; ++jj) {
      int crow = bm * 128 + wr * 64 + m * 16 + g * 4 + jj;
      size_t off = (size_t)crow * 2048 + bn * 128 + wc * 64 + r;
#pragma unroll
      for (int n = 0; n < 4; ++n) C[off + n * 16] = acc[m][n][jj];
    }
}

// ---------------------------------------------------------------------------
// MFMA flash attention (r18: KVBLK=64, 2 q-sets/wave, T14 prefetch,
// pre-transposed V b128 staging, XCD swizzle, setprio).
// ---------------------------------------------------------------------------
__global__ __launch_bounds__(256, 2)
void attn(const short* __restrict__ Q, const short* __restrict__ K,
          const short* __restrict__ VT, short* __restrict__ O) {
  __shared__ __align__(16) short Ks[64 * 136];
  __shared__ __align__(16) short Vt[128 * 72];
  __shared__ __align__(16) short Ps[4][2][16 * 72];

  const int tid = threadIdx.x;
  const int lane = tid & 63;
  const int wid = tid >> 6;
  const int g = lane >> 4, r = lane & 15;

  const int dflat = blockIdx.x + (blockIdx.y << 4);
  const int cflat = ((dflat & 7) << 6) + (dflat >> 3);
  const int qb = cflat & 15;
  const int bh = cflat >> 4;
  const int b = bh >> 4, h = bh & 15;
  const size_t base = (size_t)b * SL * EMB + (size_t)h * HD;
  const size_t vbase = (size_t)h * HD * 4096 + (size_t)b * SL;

  const int q0 = qb * 128 + wid * 32;
  s16x8 qf[2][4];
#pragma unroll
  for (int s = 0; s < 2; ++s)
#pragma unroll
    for (int kk = 0; kk < 4; ++kk)
      qf[s][kk] = *reinterpret_cast<const s16x8*>(
          Q + base + (size_t)(q0 + s * 16 + r) * EMB + kk * 32 + g * 8);

  const f32x4 fz = {0.f, 0.f, 0.f, 0.f};
  float l_run[2][4];
  f32x4 acc_o[2][8];
#pragma unroll
  for (int s = 0; s < 2; ++s) {
#pragma unroll
    for (int i = 0; i < 4; ++i) l_run[s][i] = 0.f;
#pragma unroll
    for (int i = 0; i < 8; ++i) acc_o[s][i] = fz;
  }

  const float SCALE = 0.08838834764831845f;
  const float C50I = 0.02f;
  const float CA = -1.f / 3.f, CB = 2.f / 15.f;

  const int rk = tid >> 4, ck = tid & 15;
  const int rv = tid >> 3, cv = tid & 7;
  const int cvx = cv ^ (rv & 7);
  s16x8 kreg[4], vreg[4];
#pragma unroll
  for (int i = 0; i < 4; ++i) {
    kreg[i] = *reinterpret_cast<const s16x8*>(K + base + (size_t)(rk + i * 16) * EMB + ck * 8);
    vreg[i] = *reinterpret_cast<const s16x8*>(VT + vbase + (size_t)(rv + i * 32) * 4096 + cv * 8);
  }

  for (int t = 0; t < SL / 64; ++t) {
    __syncthreads();
#pragma unroll
    for (int i = 0; i < 4; ++i) {
      *reinterpret_cast<s16x8*>(&Ks[(rk + i * 16) * 136 + ck * 8]) = kreg[i];
      *reinterpret_cast<s16x8*>(&Vt[(rv + i * 32) * 72 + (cvx << 3)]) = vreg[i];
    }
    __syncthreads();

    if (t + 1 < SL / 64) {
      const int kv1 = (t + 1) * 64;
#pragma unroll
      for (int i = 0; i < 4; ++i) {
        kreg[i] = *reinterpret_cast<const s16x8*>(K + base + (size_t)(kv1 + rk + i * 16) * EMB + ck * 8);
        vreg[i] = *reinterpret_cast<const s16x8*>(VT + vbase + (size_t)(rv + i * 32) * 4096 + kv1 + cv * 8);
      }
    }

    f32x4 sv[2][4];
    __builtin_amdgcn_s_setprio(1);
#pragma unroll
    for (int kn = 0; kn < 4; ++kn) {
      sv[0][kn] = fz; sv[1][kn] = fz;
#pragma unroll
      for (int kk = 0; kk < 4; ++kk) {
        s16x8 kf = *reinterpret_cast<const s16x8*>(&Ks[(kn * 16 + r) * 136 + kk * 32 + g * 8]);
        sv[0][kn] = MFMA_BF16(qf[0][kk], kf, sv[0][kn]);
        sv[1][kn] = MFMA_BF16(qf[1][kk], kf, sv[1][kn]);
      }
    }
    __builtin_amdgcn_s_setprio(0);

#pragma unroll
    for (int s = 0; s < 2; ++s)
#pragma unroll
      for (int kn = 0; kn < 4; ++kn)
#pragma unroll
        for (int reg = 0; reg < 4; ++reg) {
          float z = sv[s][kn][reg] * SCALE;
          float x = z * C50I;
          float x2 = x * x;
          float poly = __builtin_fmaf(x2, __builtin_fmaf(x2, CB, CA), 1.f);
          float cap = fminf(z * poly, 50.f);
          float pe = __expf(cap - 50.f);
          l_run[s][reg] += pe;
          sv[s][kn][reg] = pe;
        }

#pragma unroll
    for (int s = 0; s < 2; ++s)
#pragma unroll
      for (int kn = 0; kn < 4; ++kn)
#pragma unroll
        for (int reg = 0; reg < 4; ++reg)
          Ps[wid][s][(g * 4 + reg) * 72 + kn * 16 + r] = f2bf(sv[s][kn][reg]);

    __builtin_amdgcn_s_setprio(1);
#pragma unroll
    for (int c = 0; c < 2; ++c) {
      s16x8 pa0 = *reinterpret_cast<const s16x8*>(&Ps[wid][0][r * 72 + c * 32 + g * 8]);
      s16x8 pa1 = *reinterpret_cast<const s16x8*>(&Ps[wid][1][r * 72 + c * 32 + g * 8]);
#pragma unroll
      for (int dn = 0; dn < 8; ++dn) {
        int d = dn * 16 + r;
        int pc = ((c * 4 + g) ^ (r & 7));
        s16x8 vf = *reinterpret_cast<const s16x8*>(&Vt[d * 72 + (pc << 3)]);
        acc_o[0][dn] = MFMA_BF16(pa0, vf, acc_o[0][dn]);
        acc_o[1][dn] = MFMA_BF16(pa1, vf, acc_o[1][dn]);
      }
    }
    __builtin_amdgcn_s_setprio(0);
  }

#pragma unroll
  for (int s = 0; s < 2; ++s) {
#pragma unroll
    for (int reg = 0; reg < 4; ++reg) {
#pragma unroll
      for (int off = 1; off < 16; off <<= 1)
        l_run[s][reg] += __shfl_xor(l_run[s][reg], off);
      l_run[s][reg] = 1.f / l_run[s][reg];
    }
#pragma unroll
    for (int dn = 0; dn < 8; ++dn)
#pragma unroll
      for (int reg = 0; reg < 4; ++reg) {
        int row = q0 + s * 16 + g * 4 + reg;
        O[base + (size_t)row * EMB + dn * 16 + r] = f2bf(acc_o[s][dn][reg] * l_run[s][reg]);
      }
  }
}

__global__ void fill_f32(float* p, int n, float val) {
  int i = blockIdx.x * blockDim.x + threadIdx.x;
  if (i < n) p[i] = val;
}

// ---------------------------------------------------------------------------
extern "C" void kernel_launch(void* const* d_in, const int* in_sizes, int n_in,
                              void* d_out, int out_size, void* d_ws, size_t ws_size,
                              hipStream_t stream) {
  const float* q  = (const float*)d_in[0];
  const float* k  = (const float*)d_in[1];
  const float* v  = (const float*)d_in[2];
  const float* wq = (const float*)d_in[3];
  const float* wk = (const float*)d_in[4];
  const float* wv = (const float*)d_in[5];
  const float* wo = (const float*)d_in[6];
  float* out = (float*)d_out;

  bool ok = (n_in == 7) && out_size == 8388608;
  for (int i = 0; i < 3 && ok; ++i) ok = (in_sizes[i] == 8388608);
  for (int i = 3; i < 7 && ok; ++i) ok = (in_sizes[i] == 4194304);
  if (!ok) {
    fill_f32<<<(out_size + 255) / 256, 256, 0, stream>>>(out, out_size, 150.f);
    return;
  }

  const size_t NA = 8388608;
  const size_t NW = 4194304;
  const size_t need = (3 * NA + 4 * NW + 4 * NA) * sizeof(short); // 144 MiB
  if (ws_size < need) {
    fill_f32<<<(out_size + 255) / 256, 256, 0, stream>>>(out, out_size, 128.f);
    return;
  }

  short* bq  = (short*)d_ws;                 // cvt dst, contiguous
  short* bk  = bq + NA;
  short* bv  = bk + NA;
  short* bwq = bv + NA;
  short* bwk = bwq + NW;
  short* bwv = bwk + NW;
  short* bwo = bwv + NW;
  short* Qp  = bwo + NW;
  short* Kp  = Qp + NA;
  short* VpT = Kp + NA;                      // [2048 features][4096 tokens]
  short* Cx  = VpT + NA;

  dim3 g8(8, 16, 3);                         // 384 blocks x 512 threads
  dim3 gg(16, 32);                           // out GEMM (m97)
  dim3 ga(16, 32);                           // attn: 512 blocks

  cvt_all<<<2048, 256, 0, stream>>>(q, k, v, wq, wk, wv, wo, bq);
  gemm8_qkv<<<g8, dim3(512), 0, stream>>>(bq, bk, bwq, bwk, bwv, bv, Qp, Kp, VpT);
  attn<<<ga, dim3(256), 0, stream>>>(Qp, Kp, VpT, Cx);
  gemm_out<<<gg, dim3(256), 0, stream>>>(Cx, bwo, out);
}

// Round 24
// 320.906 us; speedup vs baseline: 4.4029x; 1.0076x over previous
//
#include <hip/hip_runtime.h>
#include <hip/hip_bf16.h>
#include <stdint.h>

// ---------------------------------------------------------------------------
// MultiheadAttention (B=2,S=2048,E=2048,H=16,D=128), softcap=50, alpha=1
// Inputs FP32, output FP32, dict-order labels (proven r8-r23).
// Round 24: split QKV dispatch to kill the 384-block grid tail (75% util):
//   gemm8_qk: z in {0,1}, 256 blocks = exactly one dispatch round (no tail)
//   gemm_vt:  VpT on the m97 128^2 structure (512 blocks, 2/CU, no tail)
// attn (r18), gemm_out (m97+T1), cvt unchanged. All components proven.
// ---------------------------------------------------------------------------

typedef __attribute__((ext_vector_type(8))) short s16x8;   // 8 bf16
typedef __attribute__((ext_vector_type(4))) float f32x4;

typedef const __attribute__((address_space(1))) char* gcptr;
typedef __attribute__((address_space(3))) char* lcptr;

#define MFMA_BF16(a, b, c) __builtin_amdgcn_mfma_f32_16x16x32_bf16((a), (b), (c), 0, 0, 0)

__device__ __forceinline__ short f2bf(float f) {          // fp32 -> bf16 RNE
  union { float f; unsigned u; } x; x.f = f;
  unsigned r = (x.u + 0x7fffu + ((x.u >> 16) & 1u)) >> 16;
  return (short)r;
}

__device__ __forceinline__ void gload16(const void* g, void* lds) {
  __builtin_amdgcn_global_load_lds((gcptr)g, (lcptr)lds, 16, 0, 0);
}

constexpr int GK = 2048;
constexpr int SL = 2048, EMB = 2048, HD = 128;

// ---------------------------------------------------------------------------
// Merged fp32 -> bf16 conversion (dst contiguous in ws).
// ---------------------------------------------------------------------------
__global__ void cvt_all(const float* __restrict__ q, const float* __restrict__ k,
                        const float* __restrict__ v, const float* __restrict__ wq,
                        const float* __restrict__ wk, const float* __restrict__ wv,
                        const float* __restrict__ wo, short* __restrict__ dst) {
  const int N8A = 1 << 20, N8W = 1 << 19;
  const int total = 3 * N8A + 4 * N8W;
  int i = blockIdx.x * blockDim.x + threadIdx.x;
  int stride = gridDim.x * blockDim.x;
  for (; i < total; i += stride) {
    const float* src;
    size_t loc;
    if (i < 3 * N8A) {
      int sel = i >> 20;
      loc = (size_t)(i & (N8A - 1));
      src = sel == 0 ? q : (sel == 1 ? k : v);
    } else {
      int w = i - 3 * N8A;
      int sel = w >> 19;
      loc = (size_t)(w & (N8W - 1));
      src = sel == 0 ? wq : (sel == 1 ? wk : (sel == 2 ? wv : wo));
    }
    f32x4 a = *reinterpret_cast<const f32x4*>(src + loc * 8);
    f32x4 b = *reinterpret_cast<const f32x4*>(src + loc * 8 + 4);
    s16x8 w8;
#pragma unroll
    for (int j = 0; j < 4; ++j) { w8[j] = f2bf(a[j]); w8[4 + j] = f2bf(b[j]); }
    *reinterpret_cast<s16x8*>(dst + (size_t)i * 8) = w8;
  }
}

// ---------------------------------------------------------------------------
// 256^2 pipelined Q/K GEMM (r20 structure, z in {0,1} only -> 256 blocks).
// ---------------------------------------------------------------------------
__global__ __launch_bounds__(512, 1)
void gemm8_qk(const short* __restrict__ a0, const short* __restrict__ a1,
              const short* __restrict__ w0, const short* __restrict__ w1,
              short* __restrict__ o0, short* __restrict__ o1) {
  __shared__ __align__(16) short Lds[4 * 16384];   // 128 KiB

  const int z = blockIdx.z;
  const short* A = z == 0 ? a0 : a1;
  const short* B = z == 0 ? w0 : w1;
  short* C = z == 0 ? o0 : o1;

  const int j = blockIdx.x + (blockIdx.y << 3);
  const int bm = ((j & 7) << 1) + ((j >> 3) & 1);
  const int bn = j >> 4;

  const int tid = threadIdx.x;
  const int lane = tid & 63;
  const int wid = tid >> 6;
  const int wm = wid >> 2, wn = wid & 3;
  const int g = lane >> 4, r = lane & 15;
  const int pg = g ^ ((r >> 1) & 3);

  const size_t Abase = (size_t)bm * 256 * GK;
  const size_t Bbase = (size_t)bn * 256 * GK;

  const f32x4 fz = {0.f, 0.f, 0.f, 0.f};
  f32x4 acc[8][4];
#pragma unroll
  for (int m = 0; m < 8; ++m)
#pragma unroll
    for (int n = 0; n < 4; ++n) acc[m][n] = fz;

  auto issueHalf = [&](int n) {
    const int reg = (n & 3) * 16384;
    const int k0 = (n << 5) & (GK - 1);
#pragma unroll
    for (int i = 0; i < 2; ++i) {
      int c = tid + i * 512;
      int row = c >> 2;
      int lg = (c & 3) ^ ((c >> 3) & 3);
      gload16(A + Abase + (size_t)row * GK + k0 + lg * 8, Lds + reg + c * 8);
    }
#pragma unroll
    for (int i = 0; i < 2; ++i) {
      int c = tid + i * 512;
      int row = c >> 2;
      int lg = (c & 3) ^ ((c >> 3) & 3);
      gload16(B + Bbase + (size_t)row * GK + k0 + lg * 8, Lds + reg + 8192 + c * 8);
    }
  };

  issueHalf(0);
  issueHalf(1);
  issueHalf(2);

  for (int t2 = 0; t2 < 16; ++t2) {
#pragma unroll
    for (int p = 0; p < 4; ++p) {
      const int n = t2 * 4 + p;
      issueHalf(n + 3);
      asm volatile("s_waitcnt vmcnt(12)" ::: "memory");
      asm volatile("s_barrier" ::: "memory");

      const int areg = p * 16384;
      s16x8 af[8], bf[4];
#pragma unroll
      for (int m = 0; m < 8; ++m)
        af[m] = *reinterpret_cast<const s16x8*>(
            Lds + areg + ((wm * 128 + m * 16 + r) << 5) + pg * 8);
#pragma unroll
      for (int nf = 0; nf < 4; ++nf)
        bf[nf] = *reinterpret_cast<const s16x8*>(
            Lds + areg + 8192 + ((wn * 64 + nf * 16 + r) << 5) + pg * 8);

      __builtin_amdgcn_s_setprio(1);
#pragma unroll
      for (int m = 0; m < 8; ++m)
#pragma unroll
        for (int nf = 0; nf < 4; ++nf)
          acc[m][nf] = MFMA_BF16(af[m], bf[nf], acc[m][nf]);
      __builtin_amdgcn_s_setprio(0);

      asm volatile("s_waitcnt lgkmcnt(0)" ::: "memory");
      asm volatile("s_barrier" ::: "memory");
    }
  }
  asm volatile("s_waitcnt vmcnt(0)" ::: "memory");

#pragma unroll
  for (int m = 0; m < 8; ++m)
#pragma unroll
    for (int jj = 0; jj < 4; ++jj) {
      int crow = bm * 256 + wm * 128 + m * 16 + g * 4 + jj;
      size_t off = (size_t)crow * 2048 + bn * 256 + wn * 64 + r;
#pragma unroll
      for (int nf = 0; nf < 4; ++nf) C[off + nf * 16] = f2bf(acc[m][nf][jj]);
    }
}

// ---------------------------------------------------------------------------
// VpT GEMM: (v @ Wv^T)^T via swapped operands (A=Wv 2048 rows, B=v 4096
// rows), m97 128^2 structure, bf16 out, gn=4096, T1 swizzle. 512 blocks.
// ---------------------------------------------------------------------------
__global__ __launch_bounds__(256, 2)
void gemm_vt(const short* __restrict__ A, const short* __restrict__ B,
             short* __restrict__ C) {
  __shared__ __align__(16) short As[128 * 64];
  __shared__ __align__(16) short Bs[128 * 64];
  const int d = blockIdx.x + (blockIdx.y << 5);        // grid (32,16)
  const int tile = ((d & 7) << 6) | (d >> 3);          // bijective, 512
  const int bm = tile >> 5, bn = tile & 31;            // 16 x 32 tiles

  const int tid = threadIdx.x;
  const int lane = tid & 63;
  const int wid = tid >> 6;
  const int wr = wid >> 1, wc = wid & 1;
  const int g = lane >> 4, r = lane & 15;

  const f32x4 fz = {0.f, 0.f, 0.f, 0.f};
  f32x4 acc[4][4];
#pragma unroll
  for (int m = 0; m < 4; ++m)
#pragma unroll
    for (int n = 0; n < 4; ++n) acc[m][n] = fz;

  const short* Ab = A + (size_t)bm * 128 * GK;
  const short* Bb = B + (size_t)bn * 128 * GK;

  for (int kt = 0; kt < GK; kt += 64) {
#pragma unroll
    for (int i = 0; i < 4; ++i) {
      int c = i * 256 + tid;
      int row = c >> 3, c8 = c & 7;
      gload16(Ab + (size_t)row * GK + kt + c8 * 8, As + c * 8);
      gload16(Bb + (size_t)row * GK + kt + c8 * 8, Bs + c * 8);
    }
    __syncthreads();
#pragma unroll
    for (int kk = 0; kk < 2; ++kk) {
      s16x8 af[4], bf[4];
#pragma unroll
      for (int m = 0; m < 4; ++m)
        af[m] = *reinterpret_cast<const s16x8*>(As + (wr * 64 + m * 16 + r) * 64 + kk * 32 + g * 8);
#pragma unroll
      for (int n = 0; n < 4; ++n)
        bf[n] = *reinterpret_cast<const s16x8*>(Bs + (wc * 64 + n * 16 + r) * 64 + kk * 32 + g * 8);
#pragma unroll
      for (int m = 0; m < 4; ++m)
#pragma unroll
        for (int n = 0; n < 4; ++n) acc[m][n] = MFMA_BF16(af[m], bf[n], acc[m][n]);
    }
    __syncthreads();
  }

#pragma unroll
  for (int m = 0; m < 4; ++m)
#pragma unroll
    for (int jj = 0; jj < 4; ++jj) {
      int crow = bm * 128 + wr * 64 + m * 16 + g * 4 + jj;
      size_t off = (size_t)crow * 4096 + bn * 128 + wc * 64 + r;
#pragma unroll
      for (int n = 0; n < 4; ++n) C[off + n * 16] = f2bf(acc[m][n][jj]);
    }
}

// ---------------------------------------------------------------------------
// Final GEMM (ctx @ Wo^T), m97 structure, fp32 out, T1 swizzle.
// ---------------------------------------------------------------------------
__global__ __launch_bounds__(256, 2)
void gemm_out(const short* __restrict__ A, const short* __restrict__ B,
              float* __restrict__ C) {
  __shared__ __align__(16) short As[128 * 64];
  __shared__ __align__(16) short Bs[128 * 64];
  const int d = blockIdx.x + (blockIdx.y << 4);
  const int tile = ((d & 7) << 6) | (d >> 3);
  const int bm = tile >> 4, bn = tile & 15;

  const int tid = threadIdx.x;
  const int lane = tid & 63;
  const int wid = tid >> 6;
  const int wr = wid >> 1, wc = wid & 1;
  const int g = lane >> 4, r = lane & 15;

  const f32x4 fz = {0.f, 0.f, 0.f, 0.f};
  f32x4 acc[4][4];
#pragma unroll
  for (int m = 0; m < 4; ++m)
#pragma unroll
    for (int n = 0; n < 4; ++n) acc[m][n] = fz;

  const short* Ab = A + (size_t)bm * 128 * GK;
  const short* Bb = B + (size_t)bn * 128 * GK;

  for (int kt = 0; kt < GK; kt += 64) {
#pragma unroll
    for (int i = 0; i < 4; ++i) {
      int c = i * 256 + tid;
      int row = c >> 3, c8 = c & 7;
      gload16(Ab + (size_t)row * GK + kt + c8 * 8, As + c * 8);
      gload16(Bb + (size_t)row * GK + kt + c8 * 8, Bs + c * 8);
    }
    __syncthreads();
#pragma unroll
    for (int kk = 0; kk < 2; ++kk) {
      s16x8 af[4], bf[4];
#pragma unroll
      for (int m = 0; m < 4; ++m)
        af[m] = *reinterpret_cast<const s16x8*>(As + (wr * 64 + m * 16 + r) * 64 + kk * 32 + g * 8);
#pragma unroll
      for (int n = 0; n < 4; ++n)
        bf[n] = *reinterpret_cast<const s16x8*>(Bs + (wc * 64 + n * 16 + r) * 64 + kk * 32 + g * 8);
#pragma unroll
      for (int m = 0; m < 4; ++m)
#pragma unroll
        for (int n = 0; n < 4; ++n) acc[m][n] = MFMA_BF16(af[m], bf[n], acc[m][n]);
    }
    __syncthreads();
  }

#pragma unroll
  for (int m = 0; m < 4; ++m)
#pragma unroll
    for (int jj = 0; jj < 4; ++jj) {
      int crow = bm * 128 + wr * 64 + m * 16 + g * 4 + jj;
      size_t off = (size_t)crow * 2048 + bn * 128 + wc * 64 + r;
#pragma unroll
      for (int n = 0; n < 4; ++n) C[off + n * 16] = acc[m][n][jj];
    }
}

// ---------------------------------------------------------------------------
// MFMA flash attention (r18, unchanged).
// ---------------------------------------------------------------------------
__global__ __launch_bounds__(256, 2)
void attn(const short* __restrict__ Q, const short* __restrict__ K,
          const short* __restrict__ VT, short* __restrict__ O) {
  __shared__ __align__(16) short Ks[64 * 136];
  __shared__ __align__(16) short Vt[128 * 72];
  __shared__ __align__(16) short Ps[4][2][16 * 72];

  const int tid = threadIdx.x;
  const int lane = tid & 63;
  const int wid = tid >> 6;
  const int g = lane >> 4, r = lane & 15;

  const int dflat = blockIdx.x + (blockIdx.y << 4);
  const int cflat = ((dflat & 7) << 6) + (dflat >> 3);
  const int qb = cflat & 15;
  const int bh = cflat >> 4;
  const int b = bh >> 4, h = bh & 15;
  const size_t base = (size_t)b * SL * EMB + (size_t)h * HD;
  const size_t vbase = (size_t)h * HD * 4096 + (size_t)b * SL;

  const int q0 = qb * 128 + wid * 32;
  s16x8 qf[2][4];
#pragma unroll
  for (int s = 0; s < 2; ++s)
#pragma unroll
    for (int kk = 0; kk < 4; ++kk)
      qf[s][kk] = *reinterpret_cast<const s16x8*>(
          Q + base + (size_t)(q0 + s * 16 + r) * EMB + kk * 32 + g * 8);

  const f32x4 fz = {0.f, 0.f, 0.f, 0.f};
  float l_run[2][4];
  f32x4 acc_o[2][8];
#pragma unroll
  for (int s = 0; s < 2; ++s) {
#pragma unroll
    for (int i = 0; i < 4; ++i) l_run[s][i] = 0.f;
#pragma unroll
    for (int i = 0; i < 8; ++i) acc_o[s][i] = fz;
  }

  const float SCALE = 0.08838834764831845f;
  const float C50I = 0.02f;
  const float CA = -1.f / 3.f, CB = 2.f / 15.f;

  const int rk = tid >> 4, ck = tid & 15;
  const int rv = tid >> 3, cv = tid & 7;
  const int cvx = cv ^ (rv & 7);
  s16x8 kreg[4], vreg[4];
#pragma unroll
  for (int i = 0; i < 4; ++i) {
    kreg[i] = *reinterpret_cast<const s16x8*>(K + base + (size_t)(rk + i * 16) * EMB + ck * 8);
    vreg[i] = *reinterpret_cast<const s16x8*>(VT + vbase + (size_t)(rv + i * 32) * 4096 + cv * 8);
  }

  for (int t = 0; t < SL / 64; ++t) {
    __syncthreads();
#pragma unroll
    for (int i = 0; i < 4; ++i) {
      *reinterpret_cast<s16x8*>(&Ks[(rk + i * 16) * 136 + ck * 8]) = kreg[i];
      *reinterpret_cast<s16x8*>(&Vt[(rv + i * 32) * 72 + (cvx << 3)]) = vreg[i];
    }
    __syncthreads();

    if (t + 1 < SL / 64) {
      const int kv1 = (t + 1) * 64;
#pragma unroll
      for (int i = 0; i < 4; ++i) {
        kreg[i] = *reinterpret_cast<const s16x8*>(K + base + (size_t)(kv1 + rk + i * 16) * EMB + ck * 8);
        vreg[i] = *reinterpret_cast<const s16x8*>(VT + vbase + (size_t)(rv + i * 32) * 4096 + kv1 + cv * 8);
      }
    }

    f32x4 sv[2][4];
    __builtin_amdgcn_s_setprio(1);
#pragma unroll
    for (int kn = 0; kn < 4; ++kn) {
      sv[0][kn] = fz; sv[1][kn] = fz;
#pragma unroll
      for (int kk = 0; kk < 4; ++kk) {
        s16x8 kf = *reinterpret_cast<const s16x8*>(&Ks[(kn * 16 + r) * 136 + kk * 32 + g * 8]);
        sv[0][kn] = MFMA_BF16(qf[0][kk], kf, sv[0][kn]);
        sv[1][kn] = MFMA_BF16(qf[1][kk], kf, sv[1][kn]);
      }
    }
    __builtin_amdgcn_s_setprio(0);

#pragma unroll
    for (int s = 0; s < 2; ++s)
#pragma unroll
      for (int kn = 0; kn < 4; ++kn)
#pragma unroll
        for (int reg = 0; reg < 4; ++reg) {
          float z = sv[s][kn][reg] * SCALE;
          float x = z * C50I;
          float x2 = x * x;
          float poly = __builtin_fmaf(x2, __builtin_fmaf(x2, CB, CA), 1.f);
          float cap = fminf(z * poly, 50.f);
          float pe = __expf(cap - 50.f);
          l_run[s][reg] += pe;
          sv[s][kn][reg] = pe;
        }

#pragma unroll
    for (int s = 0; s < 2; ++s)
#pragma unroll
      for (int kn = 0; kn < 4; ++kn)
#pragma unroll
        for (int reg = 0; reg < 4; ++reg)
          Ps[wid][s][(g * 4 + reg) * 72 + kn * 16 + r] = f2bf(sv[s][kn][reg]);

    __builtin_amdgcn_s_setprio(1);
#pragma unroll
    for (int c = 0; c < 2; ++c) {
      s16x8 pa0 = *reinterpret_cast<const s16x8*>(&Ps[wid][0][r * 72 + c * 32 + g * 8]);
      s16x8 pa1 = *reinterpret_cast<const s16x8*>(&Ps[wid][1][r * 72 + c * 32 + g * 8]);
#pragma unroll
      for (int dn = 0; dn < 8; ++dn) {
        int d = dn * 16 + r;
        int pc = ((c * 4 + g) ^ (r & 7));
        s16x8 vf = *reinterpret_cast<const s16x8*>(&Vt[d * 72 + (pc << 3)]);
        acc_o[0][dn] = MFMA_BF16(pa0, vf, acc_o[0][dn]);
        acc_o[1][dn] = MFMA_BF16(pa1, vf, acc_o[1][dn]);
      }
    }
    __builtin_amdgcn_s_setprio(0);
  }

#pragma unroll
  for (int s = 0; s < 2; ++s) {
#pragma unroll
    for (int reg = 0; reg < 4; ++reg) {
#pragma unroll
      for (int off = 1; off < 16; off <<= 1)
        l_run[s][reg] += __shfl_xor(l_run[s][reg], off);
      l_run[s][reg] = 1.f / l_run[s][reg];
    }
#pragma unroll
    for (int dn = 0; dn < 8; ++dn)
#pragma unroll
      for (int reg = 0; reg < 4; ++reg) {
        int row = q0 + s * 16 + g * 4 + reg;
        O[base + (size_t)row * EMB + dn * 16 + r] = f2bf(acc_o[s][dn][reg] * l_run[s][reg]);
      }
  }
}

__global__ void fill_f32(float* p, int n, float val) {
  int i = blockIdx.x * blockDim.x + threadIdx.x;
  if (i < n) p[i] = val;
}

// ---------------------------------------------------------------------------
extern "C" void kernel_launch(void* const* d_in, const int* in_sizes, int n_in,
                              void* d_out, int out_size, void* d_ws, size_t ws_size,
                              hipStream_t stream) {
  const float* q  = (const float*)d_in[0];
  const float* k  = (const float*)d_in[1];
  const float* v  = (const float*)d_in[2];
  const float* wq = (const float*)d_in[3];
  const float* wk = (const float*)d_in[4];
  const float* wv = (const float*)d_in[5];
  const float* wo = (const float*)d_in[6];
  float* out = (float*)d_out;

  bool ok = (n_in == 7) && out_size == 8388608;
  for (int i = 0; i < 3 && ok; ++i) ok = (in_sizes[i] == 8388608);
  for (int i = 3; i < 7 && ok; ++i) ok = (in_sizes[i] == 4194304);
  if (!ok) {
    fill_f32<<<(out_size + 255) / 256, 256, 0, stream>>>(out, out_size, 150.f);
    return;
  }

  const size_t NA = 8388608;
  const size_t NW = 4194304;
  const size_t need = (3 * NA + 4 * NW + 4 * NA) * sizeof(short); // 144 MiB
  if (ws_size < need) {
    fill_f32<<<(out_size + 255) / 256, 256, 0, stream>>>(out, out_size, 128.f);
    return;
  }

  short* bq  = (short*)d_ws;                 // cvt dst, contiguous
  short* bk  = bq + NA;
  short* bv  = bk + NA;
  short* bwq = bv + NA;
  short* bwk = bwq + NW;
  short* bwv = bwk + NW;
  short* bwo = bwv + NW;
  short* Qp  = bwo + NW;
  short* Kp  = Qp + NA;
  short* VpT = Kp + NA;                      // [2048 features][4096 tokens]
  short* Cx  = VpT + NA;

  dim3 g8(8, 16, 2);                         // 256 blocks x 512 threads (Q,K)
  dim3 gv(32, 16);                           // VpT: 512 blocks (m97)
  dim3 gg(16, 32);                           // out GEMM (m97)
  dim3 ga(16, 32);                           // attn: 512 blocks

  cvt_all<<<2048, 256, 0, stream>>>(q, k, v, wq, wk, wv, wo, bq);
  gemm8_qk<<<g8, dim3(512), 0, stream>>>(bq, bk, bwq, bwk, Qp, Kp);
  gemm_vt<<<gv, dim3(256), 0, stream>>>(bwv, bv, VpT);
  attn<<<ga, dim3(256), 0, stream>>>(Qp, Kp, VpT, Cx);
  gemm_out<<<gg, dim3(256), 0, stream>>>(Cx, bwo, out);
}